// Round 1
// baseline (775.232 us; speedup 1.0000x reference)
//
#include <hip/hip_runtime.h>
#include <stdint.h>

typedef unsigned int       u32;
typedef unsigned long long u64;
typedef unsigned short     u16;

typedef float f32x4 __attribute__((ext_vector_type(4)));
typedef short s16x8 __attribute__((ext_vector_type(8)));

#define AS1 __attribute__((address_space(1)))
#define AS3 __attribute__((address_space(3)))

constexpr int BATCH = 8, SEQ = 2048, DIM = 512, CODES = 8192;
constexpr int MROWS = BATCH * SEQ;          // 16384
constexpr int CAP   = 128;                  // candidate slots per row
#define MARGIN          1.0f                // append margin (>=16 sigma of bf16 dot err)
#define RESCORE_MARGIN  0.6f                // exact-rescore filter (~7 sigma)

// ---- ordered-uint encode for float min via atomicMin ----
__device__ __forceinline__ u32 encf(float f) {
    u32 u = __float_as_uint(f);
    return (u & 0x80000000u) ? ~u : (u | 0x80000000u);
}
__device__ __forceinline__ float decf(u32 e) {
    return (e & 0x80000000u) ? __uint_as_float(e & 0x7fffffffu) : __uint_as_float(~e);
}
__device__ __forceinline__ u16 f2bf(float f) {           // RTNE, finite inputs
    u32 u = __float_as_uint(f);
    return (u16)((u + 0x7fffu + ((u >> 16) & 1u)) >> 16);
}

// ---------------- pass 0a/0b: fp32 -> bf16 ----------------
__global__ __launch_bounds__(256) void k_cast_bf16(const float* __restrict__ src,
                                                   u16* __restrict__ dst, int n8) {
    int i = blockIdx.x * 256 + threadIdx.x;
    if (i >= n8) return;
    const float4* s = (const float4*)src + (size_t)i * 2;
    float4 a = s[0], b = s[1];
    u16 o[8];
    float v[8] = {a.x, a.y, a.z, a.w, b.x, b.y, b.z, b.w};
#pragma unroll
    for (int q = 0; q < 8; q++) o[q] = f2bf(v[q]);
    *(s16x8*)(dst + (size_t)i * 8) = *(s16x8*)o;
}

// ---------------- pass 0c/0d: numpy-pairwise-exact row sum of squares ----------------
// Replicates numpy pairwise_sum for length 512: 4 base-128 blocks (8 accumulators,
// ((r0+r1)+(r2+r3))+((r4+r5)+(r6+r7))), combined as (b0+b1)+(b2+b3).
__global__ __launch_bounds__(256) void k_rowsq(const float* __restrict__ src,
                                               float* __restrict__ dst, int rows) {
#pragma clang fp contract(off)
    int r = blockIdx.x * 256 + threadIdx.x;
    if (r >= rows) return;
    const float* a = src + (size_t)r * DIM;
    float blk[4];
    for (int b = 0; b < 4; b++) {
        const float* p = a + b * 128;
        float acc[8];
#pragma unroll
        for (int j = 0; j < 8; j++) { float t = p[j] * p[j]; acc[j] = t; }
        for (int i = 1; i < 16; i++) {
#pragma unroll
            for (int j = 0; j < 8; j++) { float t = p[i * 8 + j] * p[i * 8 + j]; acc[j] = acc[j] + t; }
        }
        blk[b] = ((acc[0] + acc[1]) + (acc[2] + acc[3])) + ((acc[4] + acc[5]) + (acc[6] + acc[7]));
    }
    dst[r] = (blk[0] + blk[1]) + (blk[2] + blk[3]);
}

__global__ __launch_bounds__(256) void k_zero(u32* __restrict__ p, int n) {
    int i = blockIdx.x * 256 + threadIdx.x;
    if (i < n) p[i] = 0u;
}

// ---------------- pass 1: bf16 MFMA GEMM + running-min + margin-append ----------------
// grid = 1024: blockIdx -> rowTile (bx>>3) x colChunk (bx&7, 1024 cols each)
__global__ __launch_bounds__(256) void k_vq(const u16* __restrict__ A,   // [16384,512] bf16
                                            const u16* __restrict__ B,   // [8192,512] bf16
                                            const float* __restrict__ c2,
                                            u32* __restrict__ cnt,
                                            uint2* __restrict__ cand) {
    __shared__ u16 lA[128 * 64];
    __shared__ u16 lB[128 * 64];
    __shared__ u32 mrow[128];

    const int t    = threadIdx.x;
    const int wave = t >> 6, lane = t & 63;
    const int lr   = lane & 15, quad = lane >> 4;
    const int bx   = blockIdx.x;
    const int row0 = (bx >> 3) * 128;
    const int col0 = (bx & 7) * 1024;
    const int wRow = (wave >> 1) * 64;
    const int wCol = (wave & 1) * 64;

    for (int i = t; i < 128; i += 256) mrow[i] = 0xFFFFFFFFu;
    __syncthreads();

    for (int ct = 0; ct < 8; ct++) {
        const int colBase = col0 + ct * 128;
        f32x4 acc[4][4];
#pragma unroll
        for (int i = 0; i < 4; i++)
#pragma unroll
            for (int j = 0; j < 4; j++) { f32x4 z = {0.f, 0.f, 0.f, 0.f}; acc[i][j] = z; }

        for (int kb = 0; kb < DIM; kb += 64) {
            // stage A,B tiles (128 rows x 64 k, bf16) via global_load_lds width-16
#pragma unroll
            for (int p = 0; p < 4; p++) {
                int off = t * 16 + p * 4096;            // byte offset in 16 KiB tile
                int rr  = off >> 7;                     // tile row (128 B/row)
                int cB  = (off & 127) >> 1;             // u16 col within 64-k window
                const u16* ga = A + (size_t)(row0 + rr) * DIM + kb + cB;
                const u16* gb = B + (size_t)(colBase + rr) * DIM + kb + cB;
                __builtin_amdgcn_global_load_lds((const AS1 u32*)ga,
                                                 (AS3 u32*)((char*)lA + off), 16, 0, 0);
                __builtin_amdgcn_global_load_lds((const AS1 u32*)gb,
                                                 (AS3 u32*)((char*)lB + off), 16, 0, 0);
            }
            __syncthreads();
#pragma unroll
            for (int kk = 0; kk < 2; kk++) {
                s16x8 af[4], bf[4];
#pragma unroll
                for (int i = 0; i < 4; i++)
                    af[i] = *(const s16x8*)&lA[(wRow + i * 16 + lr) * 64 + kk * 32 + quad * 8];
#pragma unroll
                for (int j = 0; j < 4; j++)
                    bf[j] = *(const s16x8*)&lB[(wCol + j * 16 + lr) * 64 + kk * 32 + quad * 8];
#pragma unroll
                for (int i = 0; i < 4; i++)
#pragma unroll
                    for (int j = 0; j < 4; j++)
                        acc[i][j] = __builtin_amdgcn_mfma_f32_16x16x32_bf16(af[i], bf[j], acc[i][j], 0, 0, 0);
            }
            __syncthreads();
        }

        // ---- epilogue: score = c2[col] - 2*dot; running min; margin appends ----
        float c2v[4];
#pragma unroll
        for (int j = 0; j < 4; j++) c2v[j] = c2[colBase + wCol + j * 16 + lr];

#pragma unroll
        for (int i = 0; i < 4; i++) {
#pragma unroll
            for (int r = 0; r < 4; r++) {
                float s0 = c2v[0] - 2.0f * acc[i][0][r];
                float s1 = c2v[1] - 2.0f * acc[i][1][r];
                float s2 = c2v[2] - 2.0f * acc[i][2][r];
                float s3 = c2v[3] - 2.0f * acc[i][3][r];
                float mn = fminf(fminf(s0, s1), fminf(s2, s3));
#pragma unroll
                for (int mask = 1; mask < 16; mask <<= 1)
                    mn = fminf(mn, __shfl_xor(mn, mask));
                const int lrow = wRow + i * 16 + quad * 4 + r;
                u32 key = encf(mn);
                u32 old = 0xFFFFFFFFu;
                if (lr == 0) old = atomicMin(&mrow[lrow], key);
                u32 curk = old < key ? old : key;
                curk = (u32)__shfl((int)curk, lane & 48);      // broadcast from lr==0 of group
                float thr = decf(curk) + MARGIN;
                if (mn < thr) {                                 // group-uniform
                    const int grow = row0 + lrow;
                    float ss[4] = {s0, s1, s2, s3};
#pragma unroll
                    for (int j = 0; j < 4; j++) {
                        if (ss[j] < thr) {
                            u32 idx = atomicAdd(&cnt[grow], 1u);
                            if (idx < CAP)
                                cand[(size_t)grow * CAP + idx] =
                                    make_uint2(__float_as_uint(ss[j]), (u32)(colBase + wCol + j * 16 + lr));
                        }
                    }
                }
            }
        }
    }
}

// ---------------- pass 2: exact rescore (fp64 dot, np-fp32 pipeline) + gather + PE ----------------
__global__ __launch_bounds__(256) void k_fin(const float* __restrict__ x,
                                             const float* __restrict__ cb,
                                             const float* __restrict__ c2,
                                             const float* __restrict__ x2,
                                             const u32* __restrict__ cnt,
                                             const uint2* __restrict__ cand,
                                             float* __restrict__ out) {
    const int row  = (blockIdx.x * 256 + threadIdx.x) >> 6;   // one wave per row
    const int lane = threadIdx.x & 63;
    int n = (int)cnt[row];
    if (n > CAP) n = CAP;
    const uint2* cd = cand + (size_t)row * CAP;

    // global approx min over candidate list
    float m = 3.4028235e38f;
    for (int i = lane; i < n; i += 64) m = fminf(m, __uint_as_float(cd[i].x));
#pragma unroll
    for (int mask = 32; mask; mask >>= 1) m = fminf(m, __shfl_xor(m, mask));
    const float thr = m + RESCORE_MARGIN;

    const float* xr = x + (size_t)row * DIM + lane * 8;
    float4 xv0 = *(const float4*)xr;
    float4 xv1 = *(const float4*)(xr + 4);
    const float x2v = x2[row];

    u64 best = ~0ull;
    for (int i = 0; i < n; i++) {
        uint2 e = cd[i];
        float sa = __uint_as_float(e.x);
        if (sa <= thr) {                                       // wave-uniform branch
            const float* cr = cb + (size_t)e.y * DIM + lane * 8;
            float4 c0 = *(const float4*)cr;
            float4 c1 = *(const float4*)(cr + 4);
            double d = (double)xv0.x * c0.x + (double)xv0.y * c0.y +
                       (double)xv0.z * c0.z + (double)xv0.w * c0.w +
                       (double)xv1.x * c1.x + (double)xv1.y * c1.y +
                       (double)xv1.z * c1.z + (double)xv1.w * c1.w;
#pragma unroll
            for (int mask = 32; mask; mask >>= 1) d += __shfl_xor(d, mask);
            float dot = (float)d;
            float s32 = (x2v - 2.0f * dot) + c2[e.y];          // np fp32 pipeline (2*dot exact)
            u64 key = ((u64)encf(s32) << 32) | (u64)e.y;       // lowest-index tie-break
            best = best < key ? best : key;
        }
    }
    u32 wcol = (u32)(best & 0xffffffffu);
    if (wcol >= (u32)CODES) wcol = 0;                          // unreachable safety

    // output = codebook[wcol] + PE(spos, :)
    const float* cw = cb + (size_t)wcol * DIM + lane * 8;
    float4 q0 = *(const float4*)cw;
    float4 q1 = *(const float4*)(cw + 4);
    const int spos = row & (SEQ - 1);
    float pe[8];
#pragma unroll
    for (int ii = 0; ii < 4; ii++) {
        int ipair = lane * 4 + ii;
        float dt  = expf((float)(2 * ipair) * (-0.017988946039035083f)); // ln(1e4)/512
        float ang = (float)spos * dt;
        float sv, cv;
        sincosf(ang, &sv, &cv);
        pe[2 * ii]     = sv;
        pe[2 * ii + 1] = cv;
    }
    float4* op = (float4*)(out + (size_t)row * DIM + lane * 8);
    op[0] = make_float4(q0.x + pe[0], q0.y + pe[1], q0.z + pe[2], q0.w + pe[3]);
    op[1] = make_float4(q1.x + pe[4], q1.y + pe[5], q1.z + pe[6], q1.w + pe[7]);
}

extern "C" void kernel_launch(void* const* d_in, const int* in_sizes, int n_in,
                              void* d_out, int out_size, void* d_ws, size_t ws_size,
                              hipStream_t stream) {
    const float* x  = (const float*)d_in[0];   // [8,2048,512]
    const float* cb = (const float*)d_in[1];   // [8192,512]
    float* out = (float*)d_out;

    char* ws = (char*)d_ws;
    u16*   Abf  = (u16*)ws;                                   // 16 MiB
    u16*   Bbf  = (u16*)(ws + 16777216);                      //  8 MiB
    float* c2   = (float*)(ws + 16777216 + 8388608);          // 32 KiB
    float* x2   = (float*)(ws + 16777216 + 8388608 + 32768);  // 64 KiB
    u32*   cnt  = (u32*)(ws + 16777216 + 8388608 + 32768 + 65536);            // 64 KiB
    uint2* cand = (uint2*)(ws + 16777216 + 8388608 + 32768 + 65536 + 65536);  // 16 MiB

    k_cast_bf16<<<dim3(4096), dim3(256), 0, stream>>>(x, Abf, MROWS * DIM / 8);
    k_cast_bf16<<<dim3(2048), dim3(256), 0, stream>>>(cb, Bbf, CODES * DIM / 8);
    k_rowsq<<<dim3(32), dim3(256), 0, stream>>>(cb, c2, CODES);
    k_rowsq<<<dim3(64), dim3(256), 0, stream>>>(x, x2, MROWS);
    k_zero<<<dim3(64), dim3(256), 0, stream>>>(cnt, MROWS);
    k_vq<<<dim3(1024), dim3(256), 0, stream>>>(Abf, Bbf, c2, cnt, cand);
    k_fin<<<dim3(4096), dim3(256), 0, stream>>>(x, cb, c2, x2, cnt, cand, out);
}

// Round 2
// 524.524 us; speedup vs baseline: 1.4780x; 1.4780x over previous
//
#include <hip/hip_runtime.h>
#include <stdint.h>

typedef unsigned int       u32;
typedef unsigned long long u64;
typedef unsigned short     u16;

typedef float f32x4 __attribute__((ext_vector_type(4)));
typedef short s16x8 __attribute__((ext_vector_type(8)));

#define AS1 __attribute__((address_space(1)))
#define AS3 __attribute__((address_space(3)))

constexpr int BATCH = 8, SEQ = 2048, DIM = 512, CODES = 8192;
constexpr int MROWS = BATCH * SEQ;          // 16384
constexpr int CAP   = 128;                  // candidate slots per row
#define MARGIN          1.0f                // append margin (>=13 sigma of bf16 dot err)
#define RESCORE_MARGIN  0.6f                // exact-rescore filter (~8 sigma)

// ---- ordered-uint encode for float min via atomicMin ----
__device__ __forceinline__ u32 encf(float f) {
    u32 u = __float_as_uint(f);
    return (u & 0x80000000u) ? ~u : (u | 0x80000000u);
}
__device__ __forceinline__ float decf(u32 e) {
    return (e & 0x80000000u) ? __uint_as_float(e & 0x7fffffffu) : __uint_as_float(~e);
}
__device__ __forceinline__ u16 f2bf(float f) {           // RTNE, finite inputs
    u32 u = __float_as_uint(f);
    return (u16)((u + 0x7fffu + ((u >> 16) & 1u)) >> 16);
}

// ---------------- pass 0a/0b: fp32 -> bf16 ----------------
__global__ __launch_bounds__(256) void k_cast_bf16(const float* __restrict__ src,
                                                   u16* __restrict__ dst, int n8) {
    int i = blockIdx.x * 256 + threadIdx.x;
    if (i >= n8) return;
    const float4* s = (const float4*)src + (size_t)i * 2;
    float4 a = s[0], b = s[1];
    u16 o[8];
    float v[8] = {a.x, a.y, a.z, a.w, b.x, b.y, b.z, b.w};
#pragma unroll
    for (int q = 0; q < 8; q++) o[q] = f2bf(v[q]);
    *(s16x8*)(dst + (size_t)i * 8) = *(s16x8*)o;
}

// ---------------- pass 0c/0d: numpy-pairwise-exact row sum of squares ----------------
// Replicates numpy pairwise_sum for length 512: 4 base-128 blocks (8 accumulators,
// ((r0+r1)+(r2+r3))+((r4+r5)+(r6+r7))), combined as (b0+b1)+(b2+b3).
__global__ __launch_bounds__(256) void k_rowsq(const float* __restrict__ src,
                                               float* __restrict__ dst, int rows) {
#pragma clang fp contract(off)
    int r = blockIdx.x * 256 + threadIdx.x;
    if (r >= rows) return;
    const float* a = src + (size_t)r * DIM;
    float blk[4];
    for (int b = 0; b < 4; b++) {
        const float* p = a + b * 128;
        float acc[8];
#pragma unroll
        for (int j = 0; j < 8; j++) { float t = p[j] * p[j]; acc[j] = t; }
        for (int i = 1; i < 16; i++) {
#pragma unroll
            for (int j = 0; j < 8; j++) { float t = p[i * 8 + j] * p[i * 8 + j]; acc[j] = acc[j] + t; }
        }
        blk[b] = ((acc[0] + acc[1]) + (acc[2] + acc[3])) + ((acc[4] + acc[5]) + (acc[6] + acc[7]));
    }
    dst[r] = (blk[0] + blk[1]) + (blk[2] + blk[3]);
}

__global__ __launch_bounds__(256) void k_zero(u32* __restrict__ p, int n) {
    int i = blockIdx.x * 256 + threadIdx.x;
    if (i < n) p[i] = 0u;
}

// ---------------- pass 1: bf16 MFMA GEMM + running-min + margin-append ----------------
// grid = 2048: blockIdx -> rowTile (bx>>4) x colChunk (bx&15, 512 cols each)
// LDS tiles use XOR-16B-chunk swizzle: global chunk c of row r lives at LDS
// chunk c^(r&7). Kills the 16-way bank conflict of the unswizzled 128 B stride
// while keeping the wave-uniform-base+lane*16 layout global_load_lds requires.
__global__ __launch_bounds__(256) void k_vq(const u16* __restrict__ A,   // [16384,512] bf16
                                            const u16* __restrict__ B,   // [8192,512] bf16
                                            const float* __restrict__ c2,
                                            u32* __restrict__ cnt,
                                            uint2* __restrict__ cand) {
    __shared__ u16 lA[128 * 64];
    __shared__ u16 lB[128 * 64];
    __shared__ u32 mrow[128];

    const int t    = threadIdx.x;
    const int wave = t >> 6, lane = t & 63;
    const int lr   = lane & 15, quad = lane >> 4;
    const int bx   = blockIdx.x;
    const int row0 = (bx >> 4) * 128;
    const int col0 = (bx & 15) * 512;
    const int wRow = (wave >> 1) * 64;
    const int wCol = (wave & 1) * 64;
    const int s0   = (quad ^ (lr & 7)) * 8;   // swizzled u16 chunk offset, kk=0

    for (int i = t; i < 128; i += 256) mrow[i] = 0xFFFFFFFFu;
    __syncthreads();

    for (int ct = 0; ct < 4; ct++) {
        const int colBase = col0 + ct * 128;
        f32x4 acc[4][4];
#pragma unroll
        for (int i = 0; i < 4; i++)
#pragma unroll
            for (int j = 0; j < 4; j++) { f32x4 z = {0.f, 0.f, 0.f, 0.f}; acc[i][j] = z; }

        for (int kb = 0; kb < DIM; kb += 64) {
            // stage A,B tiles (128 rows x 64 k, bf16) via global_load_lds width-16,
            // swizzling the SOURCE chunk so LDS[(r,s)] = global[r][s^(r&7)]
#pragma unroll
            for (int p = 0; p < 4; p++) {
                int off = t * 16 + p * 4096;            // byte offset in 16 KiB tile
                int rr  = off >> 7;                     // tile row (128 B/row)
                int cc  = (off >> 4) & 7;               // LDS chunk position
                int sc  = (cc ^ (rr & 7)) << 3;         // source u16 col
                const u16* ga = A + (size_t)(row0 + rr) * DIM + kb + sc;
                const u16* gb = B + (size_t)(colBase + rr) * DIM + kb + sc;
                __builtin_amdgcn_global_load_lds((const AS1 u32*)ga,
                                                 (AS3 u32*)((char*)lA + off), 16, 0, 0);
                __builtin_amdgcn_global_load_lds((const AS1 u32*)gb,
                                                 (AS3 u32*)((char*)lB + off), 16, 0, 0);
            }
            __syncthreads();
#pragma unroll
            for (int kk = 0; kk < 2; kk++) {
                const int soff = s0 ^ (kk * 32);        // (chunk ^ 4kk)*8 in u16
                s16x8 af[4], bf[4];
#pragma unroll
                for (int i = 0; i < 4; i++)
                    af[i] = *(const s16x8*)&lA[(wRow + i * 16 + lr) * 64 + soff];
#pragma unroll
                for (int j = 0; j < 4; j++)
                    bf[j] = *(const s16x8*)&lB[(wCol + j * 16 + lr) * 64 + soff];
#pragma unroll
                for (int i = 0; i < 4; i++)
#pragma unroll
                    for (int j = 0; j < 4; j++)
                        acc[i][j] = __builtin_amdgcn_mfma_f32_16x16x32_bf16(af[i], bf[j], acc[i][j], 0, 0, 0);
            }
            __syncthreads();
        }

        // ---- epilogue: score = c2[col] - 2*dot; running min; margin appends ----
        float c2v[4];
#pragma unroll
        for (int j = 0; j < 4; j++) c2v[j] = c2[colBase + wCol + j * 16 + lr];

#pragma unroll
        for (int i = 0; i < 4; i++) {
#pragma unroll
            for (int r = 0; r < 4; r++) {
                float s0v = c2v[0] - 2.0f * acc[i][0][r];
                float s1v = c2v[1] - 2.0f * acc[i][1][r];
                float s2v = c2v[2] - 2.0f * acc[i][2][r];
                float s3v = c2v[3] - 2.0f * acc[i][3][r];
                float mn = fminf(fminf(s0v, s1v), fminf(s2v, s3v));
#pragma unroll
                for (int mask = 1; mask < 16; mask <<= 1)
                    mn = fminf(mn, __shfl_xor(mn, mask));
                const int lrow = wRow + i * 16 + quad * 4 + r;
                u32 key = encf(mn);
                u32 old = 0xFFFFFFFFu;
                if (lr == 0) old = atomicMin(&mrow[lrow], key);
                u32 curk = old < key ? old : key;
                curk = (u32)__shfl((int)curk, lane & 48);      // broadcast from lr==0 of group
                float thr = decf(curk) + MARGIN;
                if (mn < thr) {                                 // group-uniform
                    const int grow = row0 + lrow;
                    float ss[4] = {s0v, s1v, s2v, s3v};
#pragma unroll
                    for (int j = 0; j < 4; j++) {
                        if (ss[j] < thr) {
                            u32 idx = atomicAdd(&cnt[grow], 1u);
                            if (idx < CAP)
                                cand[(size_t)grow * CAP + idx] =
                                    make_uint2(__float_as_uint(ss[j]), (u32)(colBase + wCol + j * 16 + lr));
                        }
                    }
                }
            }
        }
    }
}

// ---------------- pass 2: exact rescore (fp64 dot, np-fp32 pipeline) + gather + PE ----------------
__global__ __launch_bounds__(256) void k_fin(const float* __restrict__ x,
                                             const float* __restrict__ cb,
                                             const float* __restrict__ c2,
                                             const float* __restrict__ x2,
                                             const u32* __restrict__ cnt,
                                             const uint2* __restrict__ cand,
                                             float* __restrict__ out) {
    const int row  = (blockIdx.x * 256 + threadIdx.x) >> 6;   // one wave per row
    const int lane = threadIdx.x & 63;
    int n = (int)cnt[row];
    if (n > CAP) n = CAP;
    const uint2* cd = cand + (size_t)row * CAP;

    // global approx min over candidate list
    float m = 3.4028235e38f;
    for (int i = lane; i < n; i += 64) m = fminf(m, __uint_as_float(cd[i].x));
#pragma unroll
    for (int mask = 32; mask; mask >>= 1) m = fminf(m, __shfl_xor(m, mask));
    const float thr = m + RESCORE_MARGIN;

    const float* xr = x + (size_t)row * DIM + lane * 8;
    float4 xv0 = *(const float4*)xr;
    float4 xv1 = *(const float4*)(xr + 4);
    const float x2v = x2[row];

    u64 best = ~0ull;
    for (int i = 0; i < n; i++) {
        uint2 e = cd[i];
        float sa = __uint_as_float(e.x);
        if (sa <= thr) {                                       // wave-uniform branch
            const float* cr = cb + (size_t)e.y * DIM + lane * 8;
            float4 c0 = *(const float4*)cr;
            float4 c1 = *(const float4*)(cr + 4);
            double d = (double)xv0.x * c0.x + (double)xv0.y * c0.y +
                       (double)xv0.z * c0.z + (double)xv0.w * c0.w +
                       (double)xv1.x * c1.x + (double)xv1.y * c1.y +
                       (double)xv1.z * c1.z + (double)xv1.w * c1.w;
#pragma unroll
            for (int mask = 32; mask; mask >>= 1) d += __shfl_xor(d, mask);
            float dot = (float)d;
            float s32 = (x2v - 2.0f * dot) + c2[e.y];          // np fp32 pipeline (2*dot exact)
            u64 key = ((u64)encf(s32) << 32) | (u64)e.y;       // lowest-index tie-break
            best = best < key ? best : key;
        }
    }
    u32 wcol = (u32)(best & 0xffffffffu);
    if (wcol >= (u32)CODES) wcol = 0;                          // unreachable safety

    // output = codebook[wcol] + PE(spos, :)
    const float* cw = cb + (size_t)wcol * DIM + lane * 8;
    float4 q0 = *(const float4*)cw;
    float4 q1 = *(const float4*)(cw + 4);
    const int spos = row & (SEQ - 1);
    float pe[8];
#pragma unroll
    for (int ii = 0; ii < 4; ii++) {
        int ipair = lane * 4 + ii;
        float dt  = expf((float)(2 * ipair) * (-0.017988946039035083f)); // ln(1e4)/512
        float ang = (float)spos * dt;
        float sv, cv;
        sincosf(ang, &sv, &cv);
        pe[2 * ii]     = sv;
        pe[2 * ii + 1] = cv;
    }
    float4* op = (float4*)(out + (size_t)row * DIM + lane * 8);
    op[0] = make_float4(q0.x + pe[0], q0.y + pe[1], q0.z + pe[2], q0.w + pe[3]);
    op[1] = make_float4(q1.x + pe[4], q1.y + pe[5], q1.z + pe[6], q1.w + pe[7]);
}

extern "C" void kernel_launch(void* const* d_in, const int* in_sizes, int n_in,
                              void* d_out, int out_size, void* d_ws, size_t ws_size,
                              hipStream_t stream) {
    const float* x  = (const float*)d_in[0];   // [8,2048,512]
    const float* cb = (const float*)d_in[1];   // [8192,512]
    float* out = (float*)d_out;

    char* ws = (char*)d_ws;
    u16*   Abf  = (u16*)ws;                                   // 16 MiB
    u16*   Bbf  = (u16*)(ws + 16777216);                      //  8 MiB
    float* c2   = (float*)(ws + 16777216 + 8388608);          // 32 KiB
    float* x2   = (float*)(ws + 16777216 + 8388608 + 32768);  // 64 KiB
    u32*   cnt  = (u32*)(ws + 16777216 + 8388608 + 32768 + 65536);            // 64 KiB
    uint2* cand = (uint2*)(ws + 16777216 + 8388608 + 32768 + 65536 + 65536);  // 16 MiB

    k_cast_bf16<<<dim3(4096), dim3(256), 0, stream>>>(x, Abf, MROWS * DIM / 8);
    k_cast_bf16<<<dim3(2048), dim3(256), 0, stream>>>(cb, Bbf, CODES * DIM / 8);
    k_rowsq<<<dim3(32), dim3(256), 0, stream>>>(cb, c2, CODES);
    k_rowsq<<<dim3(64), dim3(256), 0, stream>>>(x, x2, MROWS);
    k_zero<<<dim3(64), dim3(256), 0, stream>>>(cnt, MROWS);
    k_vq<<<dim3(2048), dim3(256), 0, stream>>>(Abf, Bbf, c2, cnt, cand);
    k_fin<<<dim3(4096), dim3(256), 0, stream>>>(x, cb, c2, x2, cnt, cand, out);
}